// Round 9
// baseline (4866.235 us; speedup 1.0000x reference)
//
#include <hip/hip_runtime.h>
#include <math.h>

constexpr int kB  = 256;
constexpr int kT  = 512;
constexpr int kNS = 64;
constexpr int kH  = 128;

__device__ __forceinline__ float sigmoidf_(float v) { return 1.0f / (1.0f + __expf(-v)); }
__device__ __forceinline__ float dot4(float4 a, float4 b) {
    return a.x*b.x + a.y*b.y + a.z*b.z + a.w*b.w;
}

// One-time prep in d_ws: WhhT[384][128] and AT[m][n][d] (contiguous-in-d A slices).
extern "C" __global__ void __launch_bounds__(256)
prep_ws(const float* __restrict__ Whh, const float* __restrict__ A,
        float* __restrict__ WhhT, float* __restrict__ AT) {
    const int o = blockIdx.x * 256 + threadIdx.x;       // 0..98303
    if (o < 49152) {
        const int j = o >> 7, k = o & 127;
        WhhT[o] = Whh[k * 384 + j];
    } else {
        const int p = o - 49152;
        const int m = p >> 14, n = (p >> 8) & 63, d = p & 255;
        AT[p] = A[(m * 256 + d) * 64 + n];
    }
}

// One block (768 threads = 12 waves, 3/SIMD) per batch row. 3 barriers/step.
// Cache ONLY S in registers (69 floats); stream A + Whh from L2 each step.
//  P1: gh (1/2 Whh row per thread, h_t) -> K (1 row/thread, S regs)
//      -> wave-sync -> einsum (chunk=wid: wave-private K, streamed A)
//  P2: GRU+logit partials (thr 0-127) | ns reduce (128-319) | prefetch (320)
//  P3: wave 0 softmax/gate/mix/err tail
extern "C" __global__ void __launch_bounds__(768, 3)
disc_kernel(const float* __restrict__ x,   const float* __restrict__ y,
            const float* __restrict__ U,   const float* __restrict__ S,
            const float* __restrict__ Wih, const float* __restrict__ bih,
            const float* __restrict__ bhh, const float* __restrict__ Wd,
            const float* __restrict__ bd,  const float* __restrict__ WhhT,
            const float* __restrict__ AT,
            float* __restrict__ out_o,  float* __restrict__ out_p)
{
    const int b    = blockIdx.x;
    const int tid  = threadIdx.x;
    const int lane = tid & 63;
    const int wid  = tid >> 6;

    __shared__ __align__(16) float sh_K[768];
    __shared__ __align__(16) float sh_part[768];
    __shared__ __align__(16) float sh_ns[192];
    __shared__ __align__(16) float sh_gh[384];
    __shared__ __align__(16) float sh_h[2][kH];      // parity double buffer
    __shared__ __align__(16) float sh_s[kNS];
    __shared__ __align__(16) float sh_Wih[4 * 384];
    __shared__ __align__(16) float sh_bih[384];
    __shared__ __align__(16) float sh_bhh[384];
    __shared__ float sh_Wd[384];                     // row 127 zero-padded
    __shared__ float sh_bd[4];
    __shared__ float sh_enc[12];                     // per-wave K max (m = wid>>2)
    __shared__ float sh_lp[8];                       // logit partials [wave*4+m]
    __shared__ __align__(16) float sh_xt[4];
    __shared__ float sh_x2, sh_s2, sh_err;
    __shared__ float sh_yt[2];

    // ---- Persistent register cache: ONE S row (16 f4) + U + C = 69 floats --
    float4 Sa[16]; float4 Ua; float Ca;
    {
        const float4* S4 = reinterpret_cast<const float4*>(S);
        float ss = 0.f;
#pragma unroll
        for (int j = 0; j < 16; ++j) { Sa[j] = S4[tid * 16 + j]; ss += dot4(Sa[j], Sa[j]); }
        Ua = reinterpret_cast<const float4*>(U)[tid];
        Ca = -0.5f * (dot4(Ua, Ua) + ss);
    }

    // Whh half-row mapping (uniform): row = tid>>1, half = tid&1
    const int wrow = tid >> 1, whalf = tid & 1;
    const float4* Wbase = reinterpret_cast<const float4*>(WhhT) + wrow * 32 + whalf * 16;

    // Einsum task (uniform): chunk c = wid (m = wid>>2, cc = wid&3), col n = lane.
    // AT[m][n][cc*64 + d'] contiguous in d'.
    const float4* ATbase = reinterpret_cast<const float4*>(
        AT + (((wid >> 2) * 64 + lane) * 256 + (wid & 3) * 64));

    // P3-wave persistent gate state (wave 0, all lanes redundant)
    float g0 = 0.3333f, g1 = 0.3333f, g2 = 0.3334f;

    // ---- LDS preload -----------------------------------------------------
    for (int i = tid; i < 1536; i += 768) sh_Wih[i] = Wih[i];
    for (int i = tid; i < 384; i += 768) {
        sh_bih[i] = bih[i];
        sh_bhh[i] = bhh[i];
        sh_Wd[i]  = (i < 381) ? Wd[i] : 0.f;
    }
    if (tid < 3) sh_bd[tid] = bd[tid];
    if (tid < kNS) sh_s[tid] = 0.f;
    if (tid < kH)  sh_h[0][tid] = 0.f;
    if (tid == 0) {
        sh_err = 1.0f; sh_s2 = 0.f;
        float4 xv = reinterpret_cast<const float4*>(x)[(size_t)b * kT];
        reinterpret_cast<float4*>(sh_xt)[0] = xv;
        sh_x2 = dot4(xv, xv);
        sh_yt[0] = y[(size_t)b * kT];
    }
    __syncthreads();

    for (int t = 0; t < kT; ++t) {
        const int par  = t & 1;
        const int par1 = (t + 1) & 1;

        // =================== P1 ============================================
        // (a) gh: half Whh row vs h_t (L2 stream), pair-combine via shuffle
        {
            const float4* h4 = reinterpret_cast<const float4*>(sh_h[par]) + whalf * 16;
            float acc = whalf ? 0.f : sh_bhh[wrow];
#pragma unroll 4
            for (int k = 0; k < 16; ++k) acc += dot4(h4[k], Wbase[k]);
            acc += __shfl_xor(acc, 1, 64);
            if (whalf == 0) sh_gh[wrow] = acc;
        }
        // (b) A prefetch (first half of this thread's slice)
        float4 abuf[8];
#pragma unroll
        for (int j = 0; j < 8; ++j) abuf[j] = ATbase[j];
        // (c) K row tid from S regs + broadcast s reads
        {
            const float scal = -0.5f * (sh_x2 + sh_s2);
            const float4 xt4 = reinterpret_cast<const float4*>(sh_xt)[0];
            const float4* s4 = reinterpret_cast<const float4*>(sh_s);
            float d0 = 0.f, d1 = 0.f;
#pragma unroll
            for (int j = 0; j < 8; ++j) {
                d0 += dot4(s4[2*j],     Sa[2*j]);
                d1 += dot4(s4[2*j + 1], Sa[2*j + 1]);
            }
            const float kk = __expf(scal + Ca + dot4(xt4, Ua) + d0 + d1);
            sh_K[tid] = kk;
            float mx = kk;
#pragma unroll
            for (int o = 32; o > 0; o >>= 1) mx = fmaxf(mx, __shfl_xor(mx, o, 64));
            if (lane == 0) sh_enc[wid] = mx;
        }
        // Wave-sync: einsum reads ONLY own-wave K (rows 64*wid..64*wid+63)
        asm volatile("s_waitcnt lgkmcnt(0)" ::: "memory");
        // (d) einsum: 64 MACs vs wave-private K broadcast
        {
            const float4* K4 = reinterpret_cast<const float4*>(sh_K + wid * 64);
            float acc = 0.f;
#pragma unroll
            for (int j = 0; j < 8; ++j) acc += dot4(K4[j], abuf[j]);
#pragma unroll
            for (int j = 8; j < 16; ++j) acc += dot4(K4[j], ATbase[j]);
            sh_part[tid] = acc;
        }
        __syncthreads();                                  // (1)

        // =================== P2 ============================================
        if (tid < 128) {
            const float e0 = fmaxf(fmaxf(sh_enc[0], sh_enc[1]),  fmaxf(sh_enc[2],  sh_enc[3]));
            const float e1 = fmaxf(fmaxf(sh_enc[4], sh_enc[5]),  fmaxf(sh_enc[6],  sh_enc[7]));
            const float e2 = fmaxf(fmaxf(sh_enc[8], sh_enc[9]),  fmaxf(sh_enc[10], sh_enc[11]));
            const float er = sh_err;
            const int j = tid;
            const float gir = sh_bih[j]       + e0*sh_Wih[j]        + e1*sh_Wih[384 + j]
                                              + e2*sh_Wih[768 + j]  + er*sh_Wih[1152 + j];
            const float giz = sh_bih[128 + j] + e0*sh_Wih[128 + j]  + e1*sh_Wih[512 + j]
                                              + e2*sh_Wih[896 + j]  + er*sh_Wih[1280 + j];
            const float gin = sh_bih[256 + j] + e0*sh_Wih[256 + j]  + e1*sh_Wih[640 + j]
                                              + e2*sh_Wih[1024 + j] + er*sh_Wih[1408 + j];
            const float r  = sigmoidf_(gir + sh_gh[j]);
            const float z  = sigmoidf_(giz + sh_gh[128 + j]);
            const float nn = tanhf(gin + r * sh_gh[256 + j]);
            const float hn = (1.f - z) * nn + z * sh_h[par][j];
            sh_h[par1][j] = hn;
            float l0 = hn * sh_Wd[j*3+0];
            float l1 = hn * sh_Wd[j*3+1];
            float l2 = hn * sh_Wd[j*3+2];
#pragma unroll
            for (int o = 32; o > 0; o >>= 1) {
                l0 += __shfl_xor(l0, o, 64);
                l1 += __shfl_xor(l1, o, 64);
                l2 += __shfl_xor(l2, o, 64);
            }
            if (lane == 0) {
                sh_lp[wid * 4 + 0] = l0;
                sh_lp[wid * 4 + 1] = l1;
                sh_lp[wid * 4 + 2] = l2;
            }
        } else if (tid < 320) {
            const int idx = tid - 128;                     // 0..191: m = idx>>6, n = idx&63
            const int base = (idx >> 6) * 256 + (idx & 63);
            sh_ns[idx] = (sh_part[base]       + sh_part[base + 64])
                       + (sh_part[base + 128] + sh_part[base + 192]);
        } else if (tid == 320) {
            if ((t + 1) < kT) {
                float4 xv = reinterpret_cast<const float4*>(x)[(size_t)b * kT + t + 1];
                reinterpret_cast<float4*>(sh_xt)[0] = xv;
                sh_x2 = dot4(xv, xv);
                sh_yt[par1] = y[(size_t)b * kT + t + 1];
            }
        }
        __syncthreads();                                  // (2)

        // =================== P3: wave 0 tail ===============================
        if (tid < 64) {
            const float l0 = sh_lp[0] + sh_lp[4] + sh_bd[0];
            const float l1 = sh_lp[1] + sh_lp[5] + sh_bd[1];
            const float l2 = sh_lp[2] + sh_lp[6] + sh_bd[2];
            const float mx = fmaxf(l0, fmaxf(l1, l2));
            const float x0 = __expf(l0 - mx), x1 = __expf(l1 - mx), x2 = __expf(l2 - mx);
            const float theta = sigmoidf_(sh_h[par1][127]);
            const float inv = theta / (x0 + x1 + x2);
            const float omt = 1.f - theta;
            g0 = x0*inv + g0*omt;
            g1 = x1*inv + g1*omt;
            g2 = x2*inv + g2*omt;
            const float sn = g0*sh_ns[lane] + g1*sh_ns[64 + lane] + g2*sh_ns[128 + lane];
            sh_s[lane] = sn;
            if (lane == 0)
                out_p[(size_t)b * kT + t] = g0*(1.f-g0) + g1*(1.f-g1) + g2*(1.f-g2);
            if (lane == 63) {
                out_o[(size_t)b * kT + t] = sn;
                sh_err = sn - sh_yt[par];
            }
            float ss = sn * sn;
#pragma unroll
            for (int o = 32; o > 0; o >>= 1) ss += __shfl_xor(ss, o, 64);
            if (lane == 0) sh_s2 = ss;
        }
        __syncthreads();                                  // (3)
    }
}

extern "C" void kernel_launch(void* const* d_in, const int* in_sizes, int n_in,
                              void* d_out, int out_size, void* d_ws, size_t ws_size,
                              hipStream_t stream)
{
    const float* x   = (const float*)d_in[0];
    const float* y   = (const float*)d_in[1];
    const float* U   = (const float*)d_in[2];
    const float* S   = (const float*)d_in[3];
    const float* A   = (const float*)d_in[4];
    const float* Wih = (const float*)d_in[5];
    const float* Whh = (const float*)d_in[6];
    const float* bih = (const float*)d_in[7];
    const float* bhh = (const float*)d_in[8];
    const float* Wd  = (const float*)d_in[9];
    const float* bd  = (const float*)d_in[10];

    float* WhhT  = (float*)d_ws;                 // 49152 floats
    float* AT    = WhhT + 49152;                 // 49152 floats (total 384 KB)
    float* out_o = (float*)d_out;                // (B, T) preds
    float* out_p = out_o + kB * kT;              // (B, T, 1) penalties

    hipLaunchKernelGGL(prep_ws, dim3(384), dim3(256), 0, stream, Whh, A, WhhT, AT);
    hipLaunchKernelGGL(disc_kernel, dim3(kB), dim3(768), 0, stream,
                       x, y, U, S, Wih, bih, bhh, Wd, bd, WhhT, AT, out_o, out_p);
}

// Round 11
// 3939.484 us; speedup vs baseline: 1.2352x; 1.2352x over previous
//
#include <hip/hip_runtime.h>
#include <math.h>

constexpr int kB  = 256;
constexpr int kT  = 512;
constexpr int kNS = 64;
constexpr int kH  = 128;

__device__ __forceinline__ float sigmoidf_(float v) { return 1.0f / (1.0f + __expf(-v)); }
__device__ __forceinline__ float dot4(float4 a, float4 b) {
    return a.x*b.x + a.y*b.y + a.z*b.z + a.w*b.w;
}

// One-time: transpose Whh[128][384] -> WhhT[384][128] in d_ws.
extern "C" __global__ void __launch_bounds__(256)
whh_transpose(const float* __restrict__ Whh, float* __restrict__ WhhT) {
    const int o = blockIdx.x * 256 + threadIdx.x;   // 0..49151
    const int j = o >> 7, k = o & 127;
    WhhT[o] = Whh[k * 384 + j];
}

// One block (512 threads) per batch row. 3 barriers/step (R6 structure):
//   PA: K rows (regs; s read ONCE — both db halves computed, hb-selected) -> barrier
//   PB: einsum (all waves) + distributed GRU (threads 0-127)              -> barrier
//   PE: w0 tail | w1 prefetch | w2-4 gh 2 rows/thr (h read once/pair)     -> barrier
extern "C" __global__ void __launch_bounds__(512, 2)
disc_kernel(const float* __restrict__ x,   const float* __restrict__ y,
            const float* __restrict__ U,   const float* __restrict__ S,
            const float* __restrict__ A,   const float* __restrict__ Wih,
            const float* __restrict__ bih, const float* __restrict__ bhh,
            const float* __restrict__ Wd,  const float* __restrict__ bd,
            const float* __restrict__ WhhT,
            float* __restrict__ out_o,  float* __restrict__ out_p)
{
    const int b    = blockIdx.x;
    const int tid  = threadIdx.x;
    const int lane = tid & 63;
    const int wid  = tid >> 6;
    const int hb   = tid & 1;

    __shared__ __align__(16) float sh_K[768];
    __shared__ __align__(16) float sh_part[512];
    __shared__ __align__(16) float sh_part2[512];
    __shared__ __align__(16) float sh_gh[384];
    __shared__ __align__(16) float sh_h[2][kH];      // parity double buffer
    __shared__ __align__(16) float sh_s[kNS];
    __shared__ __align__(16) float sh_Wih[4 * 384];
    __shared__ __align__(16) float sh_bih[384];
    __shared__ __align__(16) float sh_bhh[384];
    __shared__ float sh_Wd[384];
    __shared__ float sh_bd[4];
    __shared__ float sh_encA[8];                     // per-wave max of kk_a
    __shared__ float sh_encB[8];                     // per-wave max of kk_b
    __shared__ __align__(16) float sh_xt[4];
    __shared__ float sh_x2, sh_s2, sh_err;
    __shared__ float sh_yt[2];

    // ---- Persistent register caches (identical layout to R6) -------------
    const float4* S4 = reinterpret_cast<const float4*>(S);
    const float4* U4 = reinterpret_cast<const float4*>(U);

    float4 Sa[16]; float4 Ua; float Ca;       // full K-row = tid
    float4 Sb[8];  float Ub0, Ub1; float Cb;  // half of K-row 512+(tid>>1)
    {
        float ss = 0.f;
#pragma unroll
        for (int j = 0; j < 16; ++j) { Sa[j] = S4[tid * 16 + j]; ss += dot4(Sa[j], Sa[j]); }
        Ua = U4[tid];
        Ca = -0.5f * (dot4(Ua, Ua) + ss);
    }
    const int pbrow = 512 + (tid >> 1);
    {
        float ss = 0.f;
#pragma unroll
        for (int j = 0; j < 8; ++j) { Sb[j] = S4[pbrow * 16 + hb * 8 + j]; ss += dot4(Sb[j], Sb[j]); }
        Ub0 = U[pbrow * 4 + hb * 2 + 0];
        Ub1 = U[pbrow * 4 + hb * 2 + 1];
        Cb = -0.5f * (Ub0*Ub0 + Ub1*Ub1 + ss);
    }
    // Einsum A caches — wave-uniform chunk mapping (conflict-free K broadcast)
    float A1[64];                              // (m=wid>>2, cc=wid&3), n=lane
#pragma unroll
    for (int dd = 0; dd < 64; ++dd)
        A1[dd] = A[((wid >> 2) * 256 + (wid & 3) * 64 + dd) * 64 + lane];
    float A2[32];                              // m=2, cc2=wid>>1, half=wid&1, n=lane
#pragma unroll
    for (int dd = 0; dd < 32; ++dd)
        A2[dd] = A[(512 + (wid >> 1) * 64 + (wid & 1) * 32 + dd) * 64 + lane];

    // PE-wave0 persistent gate state
    float g0 = 0.3333f, g1 = 0.3333f, g2 = 0.3334f;

    // ---- LDS preload -----------------------------------------------------
    for (int i = tid; i < 1536; i += 512) sh_Wih[i] = Wih[i];
    for (int i = tid; i < 384; i += 512) {
        sh_bih[i] = bih[i];
        sh_bhh[i] = bhh[i];
        sh_gh[i]  = bhh[i];                   // gh(t=0) with h=0  (R10 bug: was missing)
        sh_Wd[i]  = (i < 381) ? Wd[i] : 0.f;  // zero-pad cols 381..383
    }
    if (tid < 3) sh_bd[tid] = bd[tid];
    if (tid < kNS) sh_s[tid] = 0.f;
    if (tid < kH)  sh_h[0][tid] = 0.f;
    if (tid == 0) {
        sh_err = 1.0f; sh_s2 = 0.f;
        float4 xv = reinterpret_cast<const float4*>(x)[(size_t)b * kT];
        reinterpret_cast<float4*>(sh_xt)[0] = xv;
        sh_x2 = dot4(xv, xv);
        sh_yt[0] = y[(size_t)b * kT];
    }
    __syncthreads();

    for (int t = 0; t < kT; ++t) {
        const int par  = t & 1;
        const int par1 = (t + 1) & 1;

        // ===== PA: K rows + per-wave enc partials ==========================
        // s read ONCE (16 b128); both db pairings computed, selected by hb.
        {
            const float scal = -0.5f * (sh_x2 + sh_s2);
            const float4 xt4 = reinterpret_cast<const float4*>(sh_xt)[0];
            const float4* s4 = reinterpret_cast<const float4*>(sh_s);
            float da0 = 0.f, da1 = 0.f, dblo = 0.f, dbhi = 0.f;
#pragma unroll
            for (int j = 0; j < 8; ++j) {
                const float4 sv0 = s4[j];              // s[0..31]
                const float4 sv1 = s4[8 + j];          // s[32..63]
                da0  += dot4(sv0, Sa[j]);
                da1  += dot4(sv1, Sa[8 + j]);
                dblo += dot4(sv0, Sb[j]);              // pairing if hb==0
                dbhi += dot4(sv1, Sb[j]);              // pairing if hb==1
            }
            const float db = hb ? dbhi : dblo;
            const float kk_a = __expf(scal + Ca + dot4(xt4, Ua) + da0 + da1);
            const float xbp  = hb ? (xt4.z*Ub0 + xt4.w*Ub1) : (xt4.x*Ub0 + xt4.y*Ub1);
            const float ph   = db + Cb + xbp;
            const float po   = __shfl_xor(ph, 1, 64);
            const float kk_b = __expf(scal + ph + po);
            sh_K[tid] = kk_a;
            if (hb == 0) sh_K[512 + (tid >> 1)] = kk_b;
            float mA = kk_a, mB = kk_b;
#pragma unroll
            for (int o = 32; o > 0; o >>= 1) {
                mA = fmaxf(mA, __shfl_xor(mA, o, 64));
                mB = fmaxf(mB, __shfl_xor(mB, o, 64));
            }
            if (lane == 0) { sh_encA[wid] = mA; sh_encB[wid] = mB; }
        }
        __syncthreads();                                  // (1)

        // ===== PB: einsum (all waves) + distributed GRU (threads 0-127) ====
        {
            const float4* K4 = reinterpret_cast<const float4*>(sh_K + wid * 64);
            float acc = 0.f;
#pragma unroll
            for (int j = 0; j < 16; ++j) {                // wave-uniform broadcast
                const float4 kv = K4[j];
                acc += kv.x*A1[4*j] + kv.y*A1[4*j+1] + kv.z*A1[4*j+2] + kv.w*A1[4*j+3];
            }
            sh_part[tid] = acc;
            const float4* K4b = reinterpret_cast<const float4*>(
                                    sh_K + 512 + (wid >> 1) * 64 + (wid & 1) * 32);
            float accb = 0.f;
#pragma unroll
            for (int j = 0; j < 8; ++j) {                 // wave-uniform broadcast
                const float4 kv = K4b[j];
                accb += kv.x*A2[4*j] + kv.y*A2[4*j+1] + kv.z*A2[4*j+2] + kv.w*A2[4*j+3];
            }
            sh_part2[tid] = accb;
        }
        if (tid < 128) {
            const float e0 = fmaxf(fmaxf(sh_encA[0], sh_encA[1]), fmaxf(sh_encA[2], sh_encA[3]));
            const float e1 = fmaxf(fmaxf(sh_encA[4], sh_encA[5]), fmaxf(sh_encA[6], sh_encA[7]));
            const float e2 = fmaxf(fmaxf(fmaxf(sh_encB[0], sh_encB[1]), fmaxf(sh_encB[2], sh_encB[3])),
                                   fmaxf(fmaxf(sh_encB[4], sh_encB[5]), fmaxf(sh_encB[6], sh_encB[7])));
            const float er = sh_err;
            const int j = tid;
            const float gir = sh_bih[j]       + e0*sh_Wih[j]        + e1*sh_Wih[384 + j]
                                              + e2*sh_Wih[768 + j]  + er*sh_Wih[1152 + j];
            const float giz = sh_bih[128 + j] + e0*sh_Wih[128 + j]  + e1*sh_Wih[512 + j]
                                              + e2*sh_Wih[896 + j]  + er*sh_Wih[1280 + j];
            const float gin = sh_bih[256 + j] + e0*sh_Wih[256 + j]  + e1*sh_Wih[640 + j]
                                              + e2*sh_Wih[1024 + j] + er*sh_Wih[1408 + j];
            const float r  = sigmoidf_(gir + sh_gh[j]);
            const float z  = sigmoidf_(giz + sh_gh[128 + j]);
            const float nn = tanhf(gin + r * sh_gh[256 + j]);
            sh_h[par1][j] = (1.f - z) * nn + z * sh_h[par][j];
        }
        __syncthreads();                                  // (2)

        // ===== PE: w0 tail | w1 prefetch | w2-4 gh 2 rows/thr (h_{t+1}) ====
        if (wid == 0) {
            const float hA = sh_h[par1][lane];
            const float hB = sh_h[par1][64 + lane];
            const float theta = sigmoidf_(sh_h[par1][127]);
            float l0 = hA * sh_Wd[lane*3+0] + hB * sh_Wd[(64+lane)*3+0];
            float l1 = hA * sh_Wd[lane*3+1] + hB * sh_Wd[(64+lane)*3+1];
            float l2 = hA * sh_Wd[lane*3+2] + hB * sh_Wd[(64+lane)*3+2];
#pragma unroll
            for (int o = 32; o > 0; o >>= 1) {
                l0 += __shfl_xor(l0, o, 64);
                l1 += __shfl_xor(l1, o, 64);
                l2 += __shfl_xor(l2, o, 64);
            }
            l0 += sh_bd[0]; l1 += sh_bd[1]; l2 += sh_bd[2];
            const float mx = fmaxf(l0, fmaxf(l1, l2));
            const float x0 = __expf(l0 - mx), x1 = __expf(l1 - mx), x2 = __expf(l2 - mx);
            const float inv = theta / (x0 + x1 + x2);
            const float omt = 1.f - theta;
            g0 = x0*inv + g0*omt;
            g1 = x1*inv + g1*omt;
            g2 = x2*inv + g2*omt;
            const float ns0 = (sh_part[lane]       + sh_part[64 + lane])
                            + (sh_part[128 + lane] + sh_part[192 + lane]);
            const float ns1 = (sh_part[256 + lane] + sh_part[320 + lane])
                            + (sh_part[384 + lane] + sh_part[448 + lane]);
            const float ns2 = ((sh_part2[lane]       + sh_part2[64 + lane])
                            +  (sh_part2[128 + lane] + sh_part2[192 + lane]))
                            + ((sh_part2[256 + lane] + sh_part2[320 + lane])
                            +  (sh_part2[384 + lane] + sh_part2[448 + lane]));
            const float sn = g0*ns0 + g1*ns1 + g2*ns2;
            sh_s[lane] = sn;
            if (lane == 0)
                out_p[(size_t)b * kT + t] = g0*(1.f-g0) + g1*(1.f-g1) + g2*(1.f-g2);
            if (lane == 63) {
                out_o[(size_t)b * kT + t] = sn;
                sh_err = sn - sh_yt[par];
            }
            float ss = sn * sn;
#pragma unroll
            for (int o = 32; o > 0; o >>= 1) ss += __shfl_xor(ss, o, 64);
            if (lane == 0) sh_s2 = ss;
        } else if (wid == 1) {
            if (lane == 0 && (t + 1) < kT) {
                float4 xv = reinterpret_cast<const float4*>(x)[(size_t)b * kT + t + 1];
                reinterpret_cast<float4*>(sh_xt)[0] = xv;
                sh_x2 = dot4(xv, xv);
                sh_yt[par1] = y[(size_t)b * kT + t + 1];
            }
        } else if (tid < 320) {                            // waves 2-4: rows u, u+192
            const int u = tid - 128;                       // 0..191
            const float4* W4a = reinterpret_cast<const float4*>(WhhT) + u * 32;
            const float4* W4b = reinterpret_cast<const float4*>(WhhT) + (u + 192) * 32;
            const float4* h4  = reinterpret_cast<const float4*>(sh_h[par1]);
            float ga = sh_bhh[u], gb = sh_bhh[u + 192];
#pragma unroll 8
            for (int k4 = 0; k4 < 32; ++k4) {
                const float4 hv = h4[k4];                  // read h ONCE per pair
                ga += dot4(hv, W4a[k4]);
                gb += dot4(hv, W4b[k4]);
            }
            sh_gh[u] = ga;
            sh_gh[u + 192] = gb;
        }
        __syncthreads();                                  // (3)
    }
}

extern "C" void kernel_launch(void* const* d_in, const int* in_sizes, int n_in,
                              void* d_out, int out_size, void* d_ws, size_t ws_size,
                              hipStream_t stream)
{
    const float* x   = (const float*)d_in[0];
    const float* y   = (const float*)d_in[1];
    const float* U   = (const float*)d_in[2];
    const float* S   = (const float*)d_in[3];
    const float* A   = (const float*)d_in[4];
    const float* Wih = (const float*)d_in[5];
    const float* Whh = (const float*)d_in[6];
    const float* bih = (const float*)d_in[7];
    const float* bhh = (const float*)d_in[8];
    const float* Wd  = (const float*)d_in[9];
    const float* bd  = (const float*)d_in[10];

    float* WhhT  = (float*)d_ws;                 // 49152 floats = 192 KB scratch
    float* out_o = (float*)d_out;                // (B, T) preds
    float* out_p = out_o + kB * kT;              // (B, T, 1) penalties

    hipLaunchKernelGGL(whh_transpose, dim3(192), dim3(256), 0, stream, Whh, WhhT);
    hipLaunchKernelGGL(disc_kernel, dim3(kB), dim3(512), 0, stream,
                       x, y, U, S, A, Wih, bih, bhh, Wd, bd, WhhT, out_o, out_p);
}